// Round 4
// baseline (205.033 us; speedup 1.0000x reference)
//
#include <hip/hip_runtime.h>
#include <hip/hip_bf16.h>
#include <cstdint>
#include <cstddef>

// Problem constants (fixed by setup_inputs)
#define N_ROWS 2048
#define DIM    512
#define QN     3
#define KQ     8192
#define NCOL   (QN * KQ)   // 24576
#define NCLASS 16

#define BM 128
#define BN 128
#define BK 64
#define NBLK (NCOL / BN)   // 192 column blocks

typedef __attribute__((ext_vector_type(8))) short short8;
typedef __attribute__((ext_vector_type(4))) float f32x4;

__device__ inline unsigned short f2bf(float f) {
    uint32_t u = __float_as_uint(f);
    uint32_t r = (u + 0x7FFFu + ((u >> 16) & 1u)) >> 16;
    return (unsigned short)r;
}

// ---------------------------------------------------------------------------
// Kernel 1: L2-normalize rows of x and q_data, cast to bf16.
// One wave per row of 512 floats; 4 rows per 256-thread block.
// ---------------------------------------------------------------------------
__global__ __launch_bounds__(256) void norm_cast_kernel(
    const float* __restrict__ x, const float* __restrict__ q,
    unsigned short* __restrict__ xb, unsigned short* __restrict__ qb) {
    int row = blockIdx.x * 4 + (threadIdx.x >> 6);
    int lane = threadIdx.x & 63;
    const float* src;
    unsigned short* dst;
    if (row < N_ROWS) {
        src = x + (size_t)row * DIM;
        dst = xb + (size_t)row * DIM;
    } else {
        src = q + (size_t)(row - N_ROWS) * DIM;
        dst = qb + (size_t)(row - N_ROWS) * DIM;
    }
    float4 v0 = ((const float4*)src)[lane * 2];
    float4 v1 = ((const float4*)src)[lane * 2 + 1];
    float ss = v0.x*v0.x + v0.y*v0.y + v0.z*v0.z + v0.w*v0.w
             + v1.x*v1.x + v1.y*v1.y + v1.z*v1.z + v1.w*v1.w;
    #pragma unroll
    for (int off = 1; off < 64; off <<= 1)
        ss += __shfl_xor(ss, off, 64);
    float inv = 1.0f / fmaxf(sqrtf(ss), 1e-12f);
    float vals[8] = {v0.x, v0.y, v0.z, v0.w, v1.x, v1.y, v1.z, v1.w};
    short8 o;
    #pragma unroll
    for (int i = 0; i < 8; i++)
        o[i] = (short)f2bf(vals[i] * inv);
    *(short8*)(dst + lane * 8) = o;
}

// ---------------------------------------------------------------------------
// Kernel 2: bf16 MFMA GEMM (M=2048, N=24576, K=512).
// - XOR-swizzled LDS (round-3: bank conflicts 1.9e7 -> 0).
// - XCD-aware block decode (round-3 post-mortem: row-major dispatch spread
//   the 16 row-blocks sharing a B slab across all 8 XCDs -> each per-XCD L2
//   fetched Qb independently, FETCH_SIZE 100 MB. Decode b so each XCD owns
//   cols == xcd (mod 8) and the 16 row-blocks of a col are temporally
//   adjacent on ONE XCD: B slab fetched once per device, A once per XCD.)
// Fused epilogue: e = exp(4*sim-4), mask-weight 0, LDS row-reduce, one
// coalesced 128-float store per block into P.
// ---------------------------------------------------------------------------
__global__ __launch_bounds__(256) void gemm_epilogue_kernel(
    const unsigned short* __restrict__ Xb,   // [2048][512] bf16 bits
    const unsigned short* __restrict__ Qb,   // [24576][512] bf16 bits
    const int* __restrict__ targets,
    const int* __restrict__ q_targets,
    const int* __restrict__ order_p,
    float* __restrict__ P) {                 // [NBLK][N_ROWS] partial sums

    __shared__ unsigned short As[BM * BK];   // 16 KB
    __shared__ unsigned short Bs[BN * BK];   // 16 KB

    const int tid  = threadIdx.x;
    const int lane = tid & 63;
    const int wave = tid >> 6;               // 0..3
    const int wm = wave >> 1, wn = wave & 1;
    const int quad = lane >> 4;              // 0..3
    const int l15  = lane & 15;
    const int l7   = l15 & 7;                // row mod 8 for swizzle

    // XCD-aware decode: hardware assigns consecutive linear block IDs
    // round-robin across the 8 XCDs (heuristic, speed-only).
    const int b    = blockIdx.x;             // 0..3071
    const int xcd  = b & 7;
    const int g    = b >> 3;                 // 0..383 (position within XCD)
    const int colb = (g >> 4) * 8 + xcd;     // 0..191, cols == xcd (mod 8)
    const int rowb = g & 15;                 // 0..15
    const int m0 = rowb * BM;
    const int n0 = colb * BN;

    f32x4 acc[4][4];
    #pragma unroll
    for (int i = 0; i < 4; i++)
        #pragma unroll
        for (int j = 0; j < 4; j++)
            acc[i][j] = (f32x4){0.f, 0.f, 0.f, 0.f};

    // Staging: chunk = wave*4+j covers rows chunk*8..+7. Lane l stages
    // global row chunk*8 + (l>>3), 16B-chunk cg = (l&7) ^ (l>>3) -- the
    // inverse of the read-side swizzle. LDS dest = base + lane*16 B (fixed).
    const int stR = (lane >> 3);                       // 0..7
    const int stC = ((lane & 7) ^ stR) * 8;            // swizzled 16B chunk

    for (int k0 = 0; k0 < DIM; k0 += BK) {
        #pragma unroll
        for (int j = 0; j < 4; j++) {
            int chunk = wave * 4 + j;                 // 0..15
            int R = chunk * 8 + stR;                  // 0..127
            const unsigned short* ga = Xb + (size_t)(m0 + R) * DIM + k0 + stC;
            const unsigned short* gb = Qb + (size_t)(n0 + R) * DIM + k0 + stC;
            __builtin_amdgcn_global_load_lds(
                (const __attribute__((address_space(1))) unsigned int*)ga,
                (__attribute__((address_space(3))) unsigned int*)&As[chunk * 512 + lane * 8],
                16, 0, 0);
            __builtin_amdgcn_global_load_lds(
                (const __attribute__((address_space(1))) unsigned int*)gb,
                (__attribute__((address_space(3))) unsigned int*)&Bs[chunk * 512 + lane * 8],
                16, 0, 0);
        }
        __syncthreads();

        #pragma unroll
        for (int ks = 0; ks < BK; ks += 32) {
            short8 a[4], b2[4];
            #pragma unroll
            for (int mt = 0; mt < 4; mt++)
                a[mt] = *(const short8*)&As[(wm * 64 + mt * 16 + l15) * BK
                                            + ((((ks >> 3) + quad) ^ l7) << 3)];
            #pragma unroll
            for (int nt = 0; nt < 4; nt++)
                b2[nt] = *(const short8*)&Bs[(wn * 64 + nt * 16 + l15) * BK
                                             + ((((ks >> 3) + quad) ^ l7) << 3)];
            #pragma unroll
            for (int mt = 0; mt < 4; mt++)
                #pragma unroll
                for (int nt = 0; nt < 4; nt++)
                    acc[mt][nt] = __builtin_amdgcn_mfma_f32_16x16x32_bf16(
                        a[mt], b2[nt], acc[mt][nt], 0, 0, 0);
        }
        __syncthreads();
    }

    // ---- Epilogue: exp + mask + block row-reduction, no atomics ----
    const int ord  = order_p[0];
    const int qIdx = colb / (KQ / BN);   // block lies entirely within one queue
    const bool isOrd = (qIdx == ord);
    const int kbase = n0 - qIdx * KQ;

    int qtv[4] = {0, 0, 0, 0};
    if (isOrd) {
        #pragma unroll
        for (int nt = 0; nt < 4; nt++)
            qtv[nt] = q_targets[ord * KQ + kbase + wn * 64 + nt * 16 + l15];
    }

    // Reuse As space (all waves past final __syncthreads of the K-loop).
    float* red = (float*)As;             // red[wn*128 + local_row], 1 KB

    #pragma unroll
    for (int mt = 0; mt < 4; mt++) {
        int rowl = wm * 64 + mt * 16 + quad * 4;        // local row base
        int tg[4] = {0, 0, 0, 0};
        if (isOrd) {
            #pragma unroll
            for (int reg = 0; reg < 4; reg++) tg[reg] = targets[m0 + rowl + reg];
        }
        #pragma unroll
        for (int reg = 0; reg < 4; reg++) {
            float s = 0.f;
            #pragma unroll
            for (int nt = 0; nt < 4; nt++) {
                float sim = acc[mt][nt][reg];
                float e = __expf(4.0f * sim - 4.0f);
                if (isOrd && tg[reg] == qtv[nt]) e = 0.f;  // masked entry
                s += e;
            }
            // reduce over the 16 columns held across lanes of this quad
            s += __shfl_xor(s, 1, 64);
            s += __shfl_xor(s, 2, 64);
            s += __shfl_xor(s, 4, 64);
            s += __shfl_xor(s, 8, 64);
            if (l15 == 0)
                red[wn * 128 + rowl + reg] = s;
        }
    }
    __syncthreads();
    if (tid < 128)
        P[(size_t)colb * N_ROWS + m0 + tid] = red[tid] + red[128 + tid];
}

// ---------------------------------------------------------------------------
// Kernel 3: per-row total = sum over 192 partials (coalesced), count via
// per-wave ballot histogram, then accumulate mean(log(total/cnt)) into
// pre-zeroed out.
// ---------------------------------------------------------------------------
__global__ __launch_bounds__(256) void reduce_kernel(
    const float* __restrict__ P,
    const int* __restrict__ targets,
    const int* __restrict__ q_targets,
    const int* __restrict__ order_p,
    float* __restrict__ out) {
    __shared__ int hist[NCLASS];
    __shared__ float partial[4];
    int tid = threadIdx.x;
    int wave = tid >> 6, lane = tid & 63;
    if (tid < NCLASS) hist[tid] = 0;
    __syncthreads();
    int ord = order_p[0];

    int local[NCLASS];
    #pragma unroll
    for (int c = 0; c < NCLASS; c++) local[c] = 0;
    for (int i = tid; i < KQ; i += 256) {           // 32 iterations
        int v = q_targets[ord * KQ + i];
        #pragma unroll
        for (int c = 0; c < NCLASS; c++)
            local[c] += __popcll(__ballot(v == c)); // wave-uniform count
    }
    if (lane == 0) {
        #pragma unroll
        for (int c = 0; c < NCLASS; c++)
            atomicAdd(&hist[c], local[c]);
    }
    __syncthreads();

    int r = blockIdx.x * 256 + tid;      // 8 blocks x 256 = 2048 rows
    float total = 0.f;
    #pragma unroll 8
    for (int nb = 0; nb < NBLK; nb++)
        total += P[(size_t)nb * N_ROWS + r];   // coalesced across threads
    float cnt = (float)(QN * KQ - hist[targets[r]]);
    float v = logf(total / cnt);

    #pragma unroll
    for (int off = 1; off < 64; off <<= 1)
        v += __shfl_xor(v, off, 64);
    if (lane == 0) partial[wave] = v;
    __syncthreads();
    if (tid == 0)
        atomicAdd(out, (partial[0] + partial[1] + partial[2] + partial[3])
                       * (1.0f / (float)N_ROWS));
}

// ---------------------------------------------------------------------------
extern "C" void kernel_launch(void* const* d_in, const int* in_sizes, int n_in,
                              void* d_out, int out_size, void* d_ws, size_t ws_size,
                              hipStream_t stream) {
    const float* x         = (const float*)d_in[0];
    const float* q         = (const float*)d_in[1];
    const int*   targets   = (const int*)d_in[2];
    const int*   q_targets = (const int*)d_in[3];
    const int*   order     = (const int*)d_in[4];
    float* out = (float*)d_out;

    // Workspace: P (192*2048 f32 = 1.5 MB) | Xb (2 MB bf16) | Qb (24 MB bf16)
    char* ws = (char*)d_ws;
    float* P = (float*)ws;
    unsigned short* Xb = (unsigned short*)(ws + (size_t)NBLK * N_ROWS * 4);
    unsigned short* Qb = Xb + (size_t)N_ROWS * DIM;

    hipMemsetAsync(out, 0, sizeof(float), stream);

    norm_cast_kernel<<<(N_ROWS + NCOL) / 4, 256, 0, stream>>>(x, q, Xb, Qb);

    gemm_epilogue_kernel<<<NBLK * (N_ROWS / BM), 256, 0, stream>>>(
        Xb, Qb, targets, q_targets, order, P);

    reduce_kernel<<<N_ROWS / 256, 256, 0, stream>>>(P, targets, q_targets, order, out);
}

// Round 5
// 169.387 us; speedup vs baseline: 1.2104x; 1.2104x over previous
//
#include <hip/hip_runtime.h>
#include <hip/hip_bf16.h>
#include <cstdint>
#include <cstddef>

// Problem constants (fixed by setup_inputs)
#define N_ROWS 2048
#define DIM    512
#define QN     3
#define KQ     8192
#define NCOL   (QN * KQ)   // 24576
#define NCLASS 16

#define BM 128
#define BN 128
#define BK 128             // fp8: 128 cols = 128 B per row slab
#define NBLK (NCOL / BN)   // 192 column blocks

typedef __attribute__((ext_vector_type(4))) float f32x4;

// ---------------------------------------------------------------------------
// Kernel 1: L2-normalize rows of x and q_data, scale by 16, cast to fp8
// e4m3 (OCP). One wave per row of 512 floats; 4 rows per 256-thread block.
// Scale 16: unit-norm 512-d rows have elem sigma ~0.044 -> x16 moves the
// bulk above e4m3's 2^-6 subnormal cliff. GEMM result = 256*sim.
// ---------------------------------------------------------------------------
__global__ __launch_bounds__(256) void norm_cast_kernel(
    const float* __restrict__ x, const float* __restrict__ q,
    unsigned char* __restrict__ xb, unsigned char* __restrict__ qb) {
    int row = blockIdx.x * 4 + (threadIdx.x >> 6);
    int lane = threadIdx.x & 63;
    const float* src;
    unsigned char* dst;
    if (row < N_ROWS) {
        src = x + (size_t)row * DIM;
        dst = xb + (size_t)row * DIM;
    } else {
        src = q + (size_t)(row - N_ROWS) * DIM;
        dst = qb + (size_t)(row - N_ROWS) * DIM;
    }
    float4 v0 = ((const float4*)src)[lane * 2];
    float4 v1 = ((const float4*)src)[lane * 2 + 1];
    float ss = v0.x*v0.x + v0.y*v0.y + v0.z*v0.z + v0.w*v0.w
             + v1.x*v1.x + v1.y*v1.y + v1.z*v1.z + v1.w*v1.w;
    #pragma unroll
    for (int off = 1; off < 64; off <<= 1)
        ss += __shfl_xor(ss, off, 64);
    float inv = 16.0f / fmaxf(sqrtf(ss), 1e-12f);
    // HW fp8 pack: v_cvt_pk_fp8_f32 (src0 -> low byte, src1 -> high byte)
    int w0 = __builtin_amdgcn_cvt_pk_fp8_f32(v0.x * inv, v0.y * inv, 0,  false);
    w0     = __builtin_amdgcn_cvt_pk_fp8_f32(v0.z * inv, v0.w * inv, w0, true);
    int w1 = __builtin_amdgcn_cvt_pk_fp8_f32(v1.x * inv, v1.y * inv, 0,  false);
    w1     = __builtin_amdgcn_cvt_pk_fp8_f32(v1.z * inv, v1.w * inv, w1, true);
    uint2 o; o.x = (unsigned)w0; o.y = (unsigned)w1;
    *(uint2*)(dst + lane * 8) = o;     // 8 fp8 per lane, contiguous 512 B/row
}

// ---------------------------------------------------------------------------
// Kernel 2: fp8 MFMA GEMM (M=2048, N=24576, K=512), result = 256*sim.
// - BK=128 (fp8 halves bytes -> same 32 KB LDS, 4 K-iters / 8 barriers
//   instead of 8 / 16).
// - 16B-granular XOR swizzle: element (r,k) at LDS
//   r*128 + (((k>>4) ^ (r&7))<<4) + (k&15). fp8 rows = 128 B = 32 banks;
//   a quad's 16 lanes land on 8 distinct 16B slots x 2 rows = 2-way (free).
// - XCD-aware block decode (round-4: FETCH 100 -> 20.6 MB).
// Fused epilogue: e = exp(acc/64 - 4), mask-weight 0, LDS row-reduce, one
// coalesced 128-float store per block into P.
// ---------------------------------------------------------------------------
__global__ __launch_bounds__(256) void gemm_epilogue_kernel(
    const unsigned char* __restrict__ Xb,   // [2048][512] fp8
    const unsigned char* __restrict__ Qb,   // [24576][512] fp8
    const int* __restrict__ targets,
    const int* __restrict__ q_targets,
    const int* __restrict__ order_p,
    float* __restrict__ P) {                 // [NBLK][N_ROWS] partial sums

    __shared__ unsigned char As[BM * BK];   // 16 KB
    __shared__ unsigned char Bs[BN * BK];   // 16 KB

    const int tid  = threadIdx.x;
    const int lane = tid & 63;
    const int wave = tid >> 6;               // 0..3
    const int wm = wave >> 1, wn = wave & 1;
    const int quad = lane >> 4;              // 0..3
    const int l15  = lane & 15;
    const int l7   = l15 & 7;                // row mod 8 for swizzle

    // XCD-aware decode: consecutive linear IDs round-robin across 8 XCDs.
    const int b    = blockIdx.x;             // 0..3071
    const int xcd  = b & 7;
    const int g    = b >> 3;                 // 0..383
    const int colb = (g >> 4) * 8 + xcd;     // 0..191, cols == xcd (mod 8)
    const int rowb = g & 15;                 // 0..15
    const int m0 = rowb * BM;
    const int n0 = colb * BN;

    f32x4 acc[4][4];
    #pragma unroll
    for (int i = 0; i < 4; i++)
        #pragma unroll
        for (int j = 0; j < 4; j++)
            acc[i][j] = (f32x4){0.f, 0.f, 0.f, 0.f};

    // Staging: chunk = wave*4+j covers rows chunk*8..+7 (1 KB LDS block).
    // Lane l -> row chunk*8 + (l>>3), global 16B seg (l&7)^(l>>3) (inverse
    // of the read-side swizzle). LDS dest = base + lane*16 (fixed mapping).
    const int stR = (lane >> 3);                       // 0..7
    const int stC = ((lane & 7) ^ stR) * 16;           // byte offset in row slab

    for (int k0 = 0; k0 < DIM; k0 += BK) {
        #pragma unroll
        for (int j = 0; j < 4; j++) {
            int chunk = wave * 4 + j;                 // 0..15
            int R = chunk * 8 + stR;                  // 0..127
            const unsigned char* ga = Xb + (size_t)(m0 + R) * DIM + k0 + stC;
            const unsigned char* gb = Qb + (size_t)(n0 + R) * DIM + k0 + stC;
            __builtin_amdgcn_global_load_lds(
                (const __attribute__((address_space(1))) unsigned int*)ga,
                (__attribute__((address_space(3))) unsigned int*)&As[chunk * 1024 + lane * 16],
                16, 0, 0);
            __builtin_amdgcn_global_load_lds(
                (const __attribute__((address_space(1))) unsigned int*)gb,
                (__attribute__((address_space(3))) unsigned int*)&Bs[chunk * 1024 + lane * 16],
                16, 0, 0);
        }
        __syncthreads();

        #pragma unroll
        for (int ks = 0; ks < BK; ks += 32) {
            // frag k-range = ks + quad*8 .. +8 -> c16 = ks/16 + quad/2,
            // 8B half = quad&1. addr = row*128 + ((c16^l7)<<4) + (quad&1)*8.
            const int c16 = (ks >> 4) + (quad >> 1);
            const int sw  = ((c16 ^ l7) << 4) + (quad & 1) * 8;
            long a[4], bb[4];
            #pragma unroll
            for (int mt = 0; mt < 4; mt++)
                a[mt] = *(const long*)&As[(wm * 64 + mt * 16 + l15) * BK + sw];
            #pragma unroll
            for (int nt = 0; nt < 4; nt++)
                bb[nt] = *(const long*)&Bs[(wn * 64 + nt * 16 + l15) * BK + sw];
            #pragma unroll
            for (int mt = 0; mt < 4; mt++)
                #pragma unroll
                for (int nt = 0; nt < 4; nt++)
                    acc[mt][nt] = __builtin_amdgcn_mfma_f32_16x16x32_fp8_fp8(
                        a[mt], bb[nt], acc[mt][nt], 0, 0, 0);
        }
        __syncthreads();
    }

    // ---- Epilogue: exp + mask + block row-reduction, no atomics ----
    const int ord  = order_p[0];
    const int qIdx = colb / (KQ / BN);   // block lies entirely within one queue
    const bool isOrd = (qIdx == ord);
    const int kbase = n0 - qIdx * KQ;

    int qtv[4] = {0, 0, 0, 0};
    if (isOrd) {
        #pragma unroll
        for (int nt = 0; nt < 4; nt++)
            qtv[nt] = q_targets[ord * KQ + kbase + wn * 64 + nt * 16 + l15];
    }

    // Reuse As space (all waves past final __syncthreads of the K-loop).
    float* red = (float*)As;             // red[wn*128 + local_row], 1 KB

    #pragma unroll
    for (int mt = 0; mt < 4; mt++) {
        int rowl = wm * 64 + mt * 16 + quad * 4;        // local row base
        int tg[4] = {0, 0, 0, 0};
        if (isOrd) {
            #pragma unroll
            for (int reg = 0; reg < 4; reg++) tg[reg] = targets[m0 + rowl + reg];
        }
        #pragma unroll
        for (int reg = 0; reg < 4; reg++) {
            float s = 0.f;
            #pragma unroll
            for (int nt = 0; nt < 4; nt++) {
                float v256 = acc[mt][nt][reg];          // 256 * sim
                // e = exp(4*sim - 4) = exp(v256/64 - 4)
                float e = __expf(v256 * 0.015625f - 4.0f);
                if (isOrd && tg[reg] == qtv[nt]) e = 0.f;  // masked entry
                s += e;
            }
            // reduce over the 16 columns held across lanes of this quad
            s += __shfl_xor(s, 1, 64);
            s += __shfl_xor(s, 2, 64);
            s += __shfl_xor(s, 4, 64);
            s += __shfl_xor(s, 8, 64);
            if (l15 == 0)
                red[wn * 128 + rowl + reg] = s;
        }
    }
    __syncthreads();
    if (tid < 128)
        P[(size_t)colb * N_ROWS + m0 + tid] = red[tid] + red[128 + tid];
}

// ---------------------------------------------------------------------------
// Kernel 3: per-row total = sum over 192 partials (coalesced), count via
// per-wave ballot histogram, then accumulate mean(log(total/cnt)) into
// pre-zeroed out.
// ---------------------------------------------------------------------------
__global__ __launch_bounds__(256) void reduce_kernel(
    const float* __restrict__ P,
    const int* __restrict__ targets,
    const int* __restrict__ q_targets,
    const int* __restrict__ order_p,
    float* __restrict__ out) {
    __shared__ int hist[NCLASS];
    __shared__ float partial[4];
    int tid = threadIdx.x;
    int wave = tid >> 6, lane = tid & 63;
    if (tid < NCLASS) hist[tid] = 0;
    __syncthreads();
    int ord = order_p[0];

    int local[NCLASS];
    #pragma unroll
    for (int c = 0; c < NCLASS; c++) local[c] = 0;
    for (int i = tid; i < KQ; i += 256) {           // 32 iterations
        int v = q_targets[ord * KQ + i];
        #pragma unroll
        for (int c = 0; c < NCLASS; c++)
            local[c] += __popcll(__ballot(v == c)); // wave-uniform count
    }
    if (lane == 0) {
        #pragma unroll
        for (int c = 0; c < NCLASS; c++)
            atomicAdd(&hist[c], local[c]);
    }
    __syncthreads();

    int r = blockIdx.x * 256 + tid;      // 8 blocks x 256 = 2048 rows
    float total = 0.f;
    #pragma unroll 8
    for (int nb = 0; nb < NBLK; nb++)
        total += P[(size_t)nb * N_ROWS + r];   // coalesced across threads
    float cnt = (float)(QN * KQ - hist[targets[r]]);
    float v = logf(total / cnt);

    #pragma unroll
    for (int off = 1; off < 64; off <<= 1)
        v += __shfl_xor(v, off, 64);
    if (lane == 0) partial[wave] = v;
    __syncthreads();
    if (tid == 0)
        atomicAdd(out, (partial[0] + partial[1] + partial[2] + partial[3])
                       * (1.0f / (float)N_ROWS));
}

// ---------------------------------------------------------------------------
extern "C" void kernel_launch(void* const* d_in, const int* in_sizes, int n_in,
                              void* d_out, int out_size, void* d_ws, size_t ws_size,
                              hipStream_t stream) {
    const float* x         = (const float*)d_in[0];
    const float* q         = (const float*)d_in[1];
    const int*   targets   = (const int*)d_in[2];
    const int*   q_targets = (const int*)d_in[3];
    const int*   order     = (const int*)d_in[4];
    float* out = (float*)d_out;

    // Workspace: P (192*2048 f32 = 1.5 MB) | Xb (1 MB fp8) | Qb (12 MB fp8)
    char* ws = (char*)d_ws;
    float* P = (float*)ws;
    unsigned char* Xb = (unsigned char*)(ws + (size_t)NBLK * N_ROWS * 4);
    unsigned char* Qb = Xb + (size_t)N_ROWS * DIM;

    hipMemsetAsync(out, 0, sizeof(float), stream);

    norm_cast_kernel<<<(N_ROWS + NCOL) / 4, 256, 0, stream>>>(x, q, Xb, Qb);

    gemm_epilogue_kernel<<<NBLK * (N_ROWS / BM), 256, 0, stream>>>(
        Xb, Qb, targets, q_targets, order, P);

    reduce_kernel<<<N_ROWS / 256, 256, 0, stream>>>(P, targets, q_targets, order, out);
}

// Round 6
// 164.392 us; speedup vs baseline: 1.2472x; 1.0304x over previous
//
#include <hip/hip_runtime.h>
#include <hip/hip_bf16.h>
#include <cstdint>
#include <cstddef>

// Problem constants (fixed by setup_inputs)
#define N_ROWS 2048
#define DIM    512
#define QN     3
#define KQ     8192
#define NCOL   (QN * KQ)   // 24576
#define NCLASS 16

#define BM 128
#define BN 128
#define BK 128             // fp8: 128 cols = 128 B per row slab
#define NBLK (NCOL / BN)   // 192 column blocks

typedef __attribute__((ext_vector_type(4))) float f32x4;

// ---------------------------------------------------------------------------
// Kernel 1: L2-normalize rows of x and q_data, scale by 16, cast to fp8
// e4m3 (OCP). One wave per row; 4 rows per 256-thread block.
// Scale 16: unit-norm 512-d rows have elem sigma ~0.044 -> x16 clears
// e4m3's 2^-6 subnormal cliff. GEMM result = 256*sim.
// GLOBAL HALF-SWAP (round-5 post-mortem): rows with bit3 set store each
// 16-B chunk's two 8-B halves swapped. This bakes the 4-bit LDS XOR
// swizzle's half-bit into global memory so global_load_lds (which cannot
// permute within a 16-B load) still works, and the GEMM's b64 LDS reads
// become exactly-32-banks per quarter-wave (round 5: 6.29M conflict
// cycles = 4 extra/read from quads sharing bank parity).
// Also zeroes out[0] (replaces the hipMemsetAsync dispatch).
// ---------------------------------------------------------------------------
__global__ __launch_bounds__(256) void norm_cast_kernel(
    const float* __restrict__ x, const float* __restrict__ q,
    unsigned char* __restrict__ xb, unsigned char* __restrict__ qb,
    float* __restrict__ out) {
    if (blockIdx.x == 0 && threadIdx.x == 0) out[0] = 0.f;
    int row = blockIdx.x * 4 + (threadIdx.x >> 6);
    int lane = threadIdx.x & 63;
    const float* src;
    unsigned char* dst;
    if (row < N_ROWS) {
        src = x + (size_t)row * DIM;
        dst = xb + (size_t)row * DIM;
    } else {
        src = q + (size_t)(row - N_ROWS) * DIM;
        dst = qb + (size_t)(row - N_ROWS) * DIM;
    }
    float4 v0 = ((const float4*)src)[lane * 2];
    float4 v1 = ((const float4*)src)[lane * 2 + 1];
    float ss = v0.x*v0.x + v0.y*v0.y + v0.z*v0.z + v0.w*v0.w
             + v1.x*v1.x + v1.y*v1.y + v1.z*v1.z + v1.w*v1.w;
    #pragma unroll
    for (int off = 1; off < 64; off <<= 1)
        ss += __shfl_xor(ss, off, 64);
    float inv = 16.0f / fmaxf(sqrtf(ss), 1e-12f);
    // HW fp8 pack: v_cvt_pk_fp8_f32 (src0 -> low byte, src1 -> high byte)
    int w0 = __builtin_amdgcn_cvt_pk_fp8_f32(v0.x * inv, v0.y * inv, 0,  false);
    w0     = __builtin_amdgcn_cvt_pk_fp8_f32(v0.z * inv, v0.w * inv, w0, true);
    int w1 = __builtin_amdgcn_cvt_pk_fp8_f32(v1.x * inv, v1.y * inv, 0,  false);
    w1     = __builtin_amdgcn_cvt_pk_fp8_f32(v1.z * inv, v1.w * inv, w1, true);
    uint2 o; o.x = (unsigned)w0; o.y = (unsigned)w1;
    // half-swap bake: lane's 8 B go to (lane*8) ^ (row.bit3 * 8)
    int r3 = (row >> 3) & 1;
    *(uint2*)(dst + ((lane * 8) ^ (r3 << 3))) = o;
}

// ---------------------------------------------------------------------------
// Kernel 2: fp8 MFMA GEMM (M=2048, N=24576, K=512), result = 256*sim.
// - BK=128 (4 K-iters, 8 barriers).
// - 4-bit XOR LDS layout: element (r,k) at byte
//     r*128 + (((k>>4) ^ (r&7))<<4) + ((((k>>3)&1) ^ ((r>>3)&1))<<3) + (k&7)
//   The half-bit is pre-baked into the GLOBAL layout by norm_cast, so the
//   staging code is unchanged (wave-uniform base + lane*16, contiguous 16-B
//   fetches); only the read-side address gains one XOR. Each quad's 16
//   b64 lanes now cover all 32 banks exactly once -> zero conflicts.
// - XCD-aware block decode (round-4: FETCH 100 -> 20.6 MB).
// Fused epilogue: e = exp(acc/64 - 4), mask-weight 0, LDS row-reduce, one
// coalesced 128-float store per block into P.
// ---------------------------------------------------------------------------
__global__ __launch_bounds__(256) void gemm_epilogue_kernel(
    const unsigned char* __restrict__ Xb,   // [2048][512] fp8 (half-swapped)
    const unsigned char* __restrict__ Qb,   // [24576][512] fp8 (half-swapped)
    const int* __restrict__ targets,
    const int* __restrict__ q_targets,
    const int* __restrict__ order_p,
    float* __restrict__ P) {                 // [NBLK][N_ROWS] partial sums

    __shared__ unsigned char As[BM * BK];   // 16 KB
    __shared__ unsigned char Bs[BN * BK];   // 16 KB

    const int tid  = threadIdx.x;
    const int lane = tid & 63;
    const int wave = tid >> 6;               // 0..3
    const int wm = wave >> 1, wn = wave & 1;
    const int quad = lane >> 4;              // 0..3
    const int l15  = lane & 15;
    const int l7   = l15 & 7;                // row mod 8 for swizzle
    const int l3   = (l15 >> 3) & 1;         // row bit3 for half-swap

    // XCD-aware decode: consecutive linear IDs round-robin across 8 XCDs.
    const int b    = blockIdx.x;             // 0..3071
    const int xcd  = b & 7;
    const int g    = b >> 3;                 // 0..383
    const int colb = (g >> 4) * 8 + xcd;     // 0..191, cols == xcd (mod 8)
    const int rowb = g & 15;                 // 0..15
    const int m0 = rowb * BM;
    const int n0 = colb * BN;

    f32x4 acc[4][4];
    #pragma unroll
    for (int i = 0; i < 4; i++)
        #pragma unroll
        for (int j = 0; j < 4; j++)
            acc[i][j] = (f32x4){0.f, 0.f, 0.f, 0.f};

    // Staging: chunk = wave*4+j covers rows chunk*8..+7 (1 KB LDS block).
    // Lane l -> row chunk*8 + (l>>3), global 16B seg (l&7)^(l>>3) (inverse
    // of the read-side slot16 swizzle; the half-bit lives in global layout).
    const int stR = (lane >> 3);                       // 0..7
    const int stC = ((lane & 7) ^ stR) * 16;           // byte offset in row slab

    for (int k0 = 0; k0 < DIM; k0 += BK) {
        #pragma unroll
        for (int j = 0; j < 4; j++) {
            int chunk = wave * 4 + j;                 // 0..15
            int R = chunk * 8 + stR;                  // 0..127
            const unsigned char* ga = Xb + (size_t)(m0 + R) * DIM + k0 + stC;
            const unsigned char* gb = Qb + (size_t)(n0 + R) * DIM + k0 + stC;
            __builtin_amdgcn_global_load_lds(
                (const __attribute__((address_space(1))) unsigned int*)ga,
                (__attribute__((address_space(3))) unsigned int*)&As[chunk * 1024 + lane * 16],
                16, 0, 0);
            __builtin_amdgcn_global_load_lds(
                (const __attribute__((address_space(1))) unsigned int*)gb,
                (__attribute__((address_space(3))) unsigned int*)&Bs[chunk * 1024 + lane * 16],
                16, 0, 0);
        }
        __syncthreads();

        #pragma unroll
        for (int ks = 0; ks < BK; ks += 32) {
            // frag k-range = ks + quad*8 .. +8:
            //   16B col C = ks/16 + quad/2, half h = quad&1.
            // addr = row*128 + ((C ^ l7)<<4) + ((h ^ l3)<<3)
            const int sw = ((((ks >> 4) + (quad >> 1)) ^ l7) << 4)
                         + (((quad & 1) ^ l3) << 3);
            long a[4], bb[4];
            #pragma unroll
            for (int mt = 0; mt < 4; mt++)
                a[mt] = *(const long*)&As[(wm * 64 + mt * 16 + l15) * BK + sw];
            #pragma unroll
            for (int nt = 0; nt < 4; nt++)
                bb[nt] = *(const long*)&Bs[(wn * 64 + nt * 16 + l15) * BK + sw];
            #pragma unroll
            for (int mt = 0; mt < 4; mt++)
                #pragma unroll
                for (int nt = 0; nt < 4; nt++)
                    acc[mt][nt] = __builtin_amdgcn_mfma_f32_16x16x32_fp8_fp8(
                        a[mt], bb[nt], acc[mt][nt], 0, 0, 0);
        }
        __syncthreads();
    }

    // ---- Epilogue: exp + mask + block row-reduction, no atomics ----
    const int ord  = order_p[0];
    const int qIdx = colb / (KQ / BN);   // block lies entirely within one queue
    const bool isOrd = (qIdx == ord);
    const int kbase = n0 - qIdx * KQ;

    int qtv[4] = {0, 0, 0, 0};
    if (isOrd) {
        #pragma unroll
        for (int nt = 0; nt < 4; nt++)
            qtv[nt] = q_targets[ord * KQ + kbase + wn * 64 + nt * 16 + l15];
    }

    // Reuse As space (all waves past final __syncthreads of the K-loop).
    float* red = (float*)As;             // red[wn*128 + local_row], 1 KB

    #pragma unroll
    for (int mt = 0; mt < 4; mt++) {
        int rowl = wm * 64 + mt * 16 + quad * 4;        // local row base
        int tg[4] = {0, 0, 0, 0};
        if (isOrd) {
            #pragma unroll
            for (int reg = 0; reg < 4; reg++) tg[reg] = targets[m0 + rowl + reg];
        }
        #pragma unroll
        for (int reg = 0; reg < 4; reg++) {
            float s = 0.f;
            #pragma unroll
            for (int nt = 0; nt < 4; nt++) {
                float v256 = acc[mt][nt][reg];          // 256 * sim
                // e = exp(4*sim - 4) = exp(v256/64 - 4)
                float e = __expf(v256 * 0.015625f - 4.0f);
                if (isOrd && tg[reg] == qtv[nt]) e = 0.f;  // masked entry
                s += e;
            }
            // reduce over the 16 columns held across lanes of this quad
            s += __shfl_xor(s, 1, 64);
            s += __shfl_xor(s, 2, 64);
            s += __shfl_xor(s, 4, 64);
            s += __shfl_xor(s, 8, 64);
            if (l15 == 0)
                red[wn * 128 + rowl + reg] = s;
        }
    }
    __syncthreads();
    if (tid < 128)
        P[(size_t)colb * N_ROWS + m0 + tid] = red[tid] + red[128 + tid];
}

// ---------------------------------------------------------------------------
// Kernel 3: per-row total = sum over 192 partials (coalesced), count via
// per-wave ballot histogram, then accumulate mean(log(total/cnt)) into
// out (zeroed by norm_cast earlier in the stream).
// ---------------------------------------------------------------------------
__global__ __launch_bounds__(256) void reduce_kernel(
    const float* __restrict__ P,
    const int* __restrict__ targets,
    const int* __restrict__ q_targets,
    const int* __restrict__ order_p,
    float* __restrict__ out) {
    __shared__ int hist[NCLASS];
    __shared__ float partial[4];
    int tid = threadIdx.x;
    int wave = tid >> 6, lane = tid & 63;
    if (tid < NCLASS) hist[tid] = 0;
    __syncthreads();
    int ord = order_p[0];

    int local[NCLASS];
    #pragma unroll
    for (int c = 0; c < NCLASS; c++) local[c] = 0;
    for (int i = tid; i < KQ; i += 256) {           // 32 iterations
        int v = q_targets[ord * KQ + i];
        #pragma unroll
        for (int c = 0; c < NCLASS; c++)
            local[c] += __popcll(__ballot(v == c)); // wave-uniform count
    }
    if (lane == 0) {
        #pragma unroll
        for (int c = 0; c < NCLASS; c++)
            atomicAdd(&hist[c], local[c]);
    }
    __syncthreads();

    int r = blockIdx.x * 256 + tid;      // 8 blocks x 256 = 2048 rows
    float total = 0.f;
    #pragma unroll 8
    for (int nb = 0; nb < NBLK; nb++)
        total += P[(size_t)nb * N_ROWS + r];   // coalesced across threads
    float cnt = (float)(QN * KQ - hist[targets[r]]);
    float v = logf(total / cnt);

    #pragma unroll
    for (int off = 1; off < 64; off <<= 1)
        v += __shfl_xor(v, off, 64);
    if (lane == 0) partial[wave] = v;
    __syncthreads();
    if (tid == 0)
        atomicAdd(out, (partial[0] + partial[1] + partial[2] + partial[3])
                       * (1.0f / (float)N_ROWS));
}

// ---------------------------------------------------------------------------
extern "C" void kernel_launch(void* const* d_in, const int* in_sizes, int n_in,
                              void* d_out, int out_size, void* d_ws, size_t ws_size,
                              hipStream_t stream) {
    const float* x         = (const float*)d_in[0];
    const float* q         = (const float*)d_in[1];
    const int*   targets   = (const int*)d_in[2];
    const int*   q_targets = (const int*)d_in[3];
    const int*   order     = (const int*)d_in[4];
    float* out = (float*)d_out;

    // Workspace: P (192*2048 f32 = 1.5 MB) | Xb (1 MB fp8) | Qb (12 MB fp8)
    char* ws = (char*)d_ws;
    float* P = (float*)ws;
    unsigned char* Xb = (unsigned char*)(ws + (size_t)NBLK * N_ROWS * 4);
    unsigned char* Qb = Xb + (size_t)N_ROWS * DIM;

    norm_cast_kernel<<<(N_ROWS + NCOL) / 4, 256, 0, stream>>>(x, q, Xb, Qb, out);

    gemm_epilogue_kernel<<<NBLK * (N_ROWS / BM), 256, 0, stream>>>(
        Xb, Qb, targets, q_targets, order, P);

    reduce_kernel<<<N_ROWS / 256, 256, 0, stream>>>(P, targets, q_targets, order, out);
}